// Round 4
// baseline (299.053 us; speedup 1.0000x reference)
//
#include <hip/hip_runtime.h>
#include <hip/hip_bf16.h>

// Problem constants
#define LSP  6272   // 8*28*28 spatial
#define LK   784    // 4*14*14 pooled spatial
#define CIN  512
#define CQo  64
#define CVo  256
#define NB   4

typedef __bf16  bf16x8 __attribute__((ext_vector_type(8)));
typedef __bf16  bf16x4 __attribute__((ext_vector_type(4)));
typedef float   f32x4  __attribute__((ext_vector_type(4)));

#define LDT  40   // padded LDS row (bf16 elems): 80 B = 16*5, keeps b128 aligned

// ---------------------------------------------------------------------------
// K0b: weight prep. Wqkv bf16 [384][512]; Wzb bf16 [512][256]
// ---------------------------------------------------------------------------
__global__ void wprep_kernel(const float* __restrict__ Wq, const float* __restrict__ Wk,
                             const float* __restrict__ Wv, const float* __restrict__ Wz,
                             __bf16* __restrict__ Wqkv, __bf16* __restrict__ Wzb)
{
    int idx = blockIdx.x * 256 + threadIdx.x;
    if (idx < 384 * 512) {
        int o = idx >> 9;
        float v = (o < 64) ? Wq[idx] : (o < 128) ? Wk[idx - 64 * 512] : Wv[idx - 128 * 512];
        Wqkv[idx] = (__bf16)v;
    }
    if (idx < 512 * 256) Wzb[idx] = (__bf16)Wz[idx];
}

// ---------------------------------------------------------------------------
// K1: QKV MFMA GEMM with fused x transpose+convert (xT kernel eliminated).
// out[o][p] = sum_c Wqkv[o][c] * x[n][c][p];  x staged fp32->bf16 into LDS as
// [p][c] with column XOR-swizzle (write conflicts 8->4 way).
// m0==0 (q,k):  A=W(o rows),  B=x(p rows) -> D[o][p] col=p  -> store qT/kT[p][o] bf16x4
// m0>0  (v):    A=x(p rows),  B=W(cv rows)-> D[p][cv] col=cv -> store vconv[cv][p] bf16x4
// ---------------------------------------------------------------------------
__global__ __launch_bounds__(256) void qkv_gemm(const __bf16* __restrict__ Wqkv,
                                                const float* __restrict__ x,
                                                __bf16* __restrict__ qT,
                                                __bf16* __restrict__ kT,
                                                __bf16* __restrict__ vconv)
{
    __shared__ __attribute__((aligned(16))) __bf16 As[128 * LDT];
    __shared__ __attribute__((aligned(16))) __bf16 Bs[128 * LDT];
    int t = threadIdx.x;
    int p0 = blockIdx.x * 128;
    int m0 = blockIdx.y * 128;
    int n  = blockIdx.z;
    int lane = t & 63, wid = t >> 6;
    int wm = wid >> 1, wn = wid & 1;
    int lm = lane & 15, lk = lane >> 4;
    int cS = t >> 3, pqS = t & 7;          // staging coords: channel, p-quad

    f32x4 acc[4][4] = {};

    for (int kb = 0; kb < CIN; kb += 32) {
        // --- stage A: W rows [128 o][32 c] ---
        #pragma unroll
        for (int i = 0; i < 2; i++) {
            int idx = i * 2048 + t * 8;
            int r = idx >> 5, k8 = idx & 31;
            *reinterpret_cast<uint4*>(&As[r * LDT + k8]) =
                *reinterpret_cast<const uint4*>(&Wqkv[(size_t)(m0 + r) * CIN + kb + k8]);
        }
        // --- stage B: x [32 c][128 p] fp32 -> Bs [p][c^swz] bf16 ---
        #pragma unroll
        for (int i = 0; i < 4; i++) {
            int p = i * 32 + pqS * 4;
            const float4 v = *reinterpret_cast<const float4*>(
                &x[((size_t)(n * CIN + kb + cS)) * LSP + p0 + p]);
            int csw = cS ^ ((pqS & 3) << 3);
            Bs[(p + 0) * LDT + csw] = (__bf16)v.x;
            Bs[(p + 1) * LDT + csw] = (__bf16)v.y;
            Bs[(p + 2) * LDT + csw] = (__bf16)v.z;
            Bs[(p + 3) * LDT + csw] = (__bf16)v.w;
        }
        __syncthreads();
        if (m0 == 0) {
            bf16x8 a[4], b[4];
            #pragma unroll
            for (int mi = 0; mi < 4; mi++)
                a[mi] = *reinterpret_cast<const bf16x8*>(&As[(wm * 64 + mi * 16 + lm) * LDT + lk * 8]);
            #pragma unroll
            for (int ni = 0; ni < 4; ni++) {
                int row = wn * 64 + ni * 16 + lm;
                b[ni] = *reinterpret_cast<const bf16x8*>(
                    &Bs[row * LDT + ((lk * 8) ^ (((row >> 2) & 3) << 3))]);
            }
            #pragma unroll
            for (int mi = 0; mi < 4; mi++)
                #pragma unroll
                for (int ni = 0; ni < 4; ni++)
                    acc[mi][ni] = __builtin_amdgcn_mfma_f32_16x16x32_bf16(a[mi], b[ni], acc[mi][ni], 0, 0, 0);
        } else {
            bf16x8 a[4], b[4];
            #pragma unroll
            for (int mi = 0; mi < 4; mi++) {
                int row = wn * 64 + mi * 16 + lm;
                a[mi] = *reinterpret_cast<const bf16x8*>(
                    &Bs[row * LDT + ((lk * 8) ^ (((row >> 2) & 3) << 3))]);
            }
            #pragma unroll
            for (int ni = 0; ni < 4; ni++)
                b[ni] = *reinterpret_cast<const bf16x8*>(&As[(wm * 64 + ni * 16 + lm) * LDT + lk * 8]);
            #pragma unroll
            for (int mi = 0; mi < 4; mi++)
                #pragma unroll
                for (int ni = 0; ni < 4; ni++)
                    acc[mi][ni] = __builtin_amdgcn_mfma_f32_16x16x32_bf16(a[mi], b[ni], acc[mi][ni], 0, 0, 0);
        }
        __syncthreads();
    }

    if (m0 == 0) {
        #pragma unroll
        for (int mi = 0; mi < 4; mi++) {
            int mloc = wm * 64 + mi * 16 + lk * 4;
            #pragma unroll
            for (int ni = 0; ni < 4; ni++) {
                int p = p0 + wn * 64 + ni * 16 + lm;
                bf16x4 o;
                o[0] = (__bf16)acc[mi][ni][0]; o[1] = (__bf16)acc[mi][ni][1];
                o[2] = (__bf16)acc[mi][ni][2]; o[3] = (__bf16)acc[mi][ni][3];
                if (mloc < 64)
                    *reinterpret_cast<bf16x4*>(&qT[((size_t)(n * LSP + p)) * 64 + mloc]) = o;
                else
                    *reinterpret_cast<bf16x4*>(&kT[((size_t)(n * LSP + p)) * 64 + (mloc - 64)]) = o;
            }
        }
    } else {
        #pragma unroll
        for (int mi = 0; mi < 4; mi++) {
            int p = p0 + wn * 64 + mi * 16 + lk * 4;
            #pragma unroll
            for (int ni = 0; ni < 4; ni++) {
                int cv = (m0 - 128) + wm * 64 + ni * 16 + lm;
                bf16x4 o;
                o[0] = (__bf16)acc[mi][ni][0]; o[1] = (__bf16)acc[mi][ni][1];
                o[2] = (__bf16)acc[mi][ni][2]; o[3] = (__bf16)acc[mi][ni][3];
                *reinterpret_cast<bf16x4*>(&vconv[((size_t)(n * CVo + cv)) * LSP + p]) = o;
            }
        }
    }
}

// ---------------------------------------------------------------------------
// K2a: pool kT [n][p][64] -> kpT [n][784][64]
// ---------------------------------------------------------------------------
__global__ __launch_bounds__(256) void poolk_kernel(const __bf16* __restrict__ kT,
                                                    __bf16* __restrict__ kpT)
{
    int wid = threadIdx.x >> 6, lane = threadIdx.x & 63;
    int row = blockIdx.x * 4 + wid;
    int n = row / LK, pk = row % LK;
    int tp = pk / 196, rem = pk % 196, hp = rem / 14, wp = rem % 14;
    const __bf16* b = kT + ((size_t)n * LSP + tp * 2 * 784 + hp * 2 * 28 + wp * 2) * 64 + lane;
    float m =        (float)b[0];
    m = fmaxf(m, (float)b[64]);
    m = fmaxf(m, (float)b[28 * 64]);
    m = fmaxf(m, (float)b[29 * 64]);
    m = fmaxf(m, (float)b[784 * 64]);
    m = fmaxf(m, (float)b[785 * 64]);
    m = fmaxf(m, (float)b[812 * 64]);
    m = fmaxf(m, (float)b[813 * 64]);
    kpT[(size_t)row * 64 + lane] = (__bf16)m;
}

// ---------------------------------------------------------------------------
// K2b: pool vconv [n][cv][p] -> vp [n][cv][784]
// ---------------------------------------------------------------------------
__global__ void poolv_kernel(const __bf16* __restrict__ vconv, __bf16* __restrict__ vp)
{
    int id = blockIdx.x * 256 + threadIdx.x;
    if (id >= NB * CVo * LK) return;
    int nc = id / LK, pk = id % LK;
    int tp = pk / 196, rem = pk % 196, hp = rem / 14, wp = rem % 14;
    const __bf16* b = vconv + (size_t)nc * LSP + tp * 2 * 784 + hp * 2 * 28 + wp * 2;
    float m =        (float)b[0];
    m = fmaxf(m, (float)b[1]);   m = fmaxf(m, (float)b[28]);  m = fmaxf(m, (float)b[29]);
    m = fmaxf(m, (float)b[784]); m = fmaxf(m, (float)b[785]); m = fmaxf(m, (float)b[812]); m = fmaxf(m, (float)b[813]);
    vp[id] = (__bf16)m;
}

// ---------------------------------------------------------------------------
// K3: flash attention v2 — 1 wave per 16 q rows, fully independent (no barriers).
// S^T via mfma(A=K, B=Q): lane owns q=lm, k in-lane -> in-lane online softmax
// (2 shfl_xor per reduce), T13 defer-max, P -> 2KB swizzled LDS, PV A=V, B=P.
// Grid: (392 q-tiles, 4 n), 64 threads.
// ---------------------------------------------------------------------------
__global__ __launch_bounds__(64, 2) void flash2_kernel(
    const __bf16* __restrict__ qT, const __bf16* __restrict__ kpT,
    const __bf16* __restrict__ vp, __bf16* __restrict__ attT)
{
    __shared__ __attribute__((aligned(16))) __bf16 Ps[16 * 64];   // [q=16][k=64]
    int lane = threadIdx.x;
    int lm = lane & 15, lk = lane >> 4;
    int q0 = blockIdx.x * 16;
    int n  = blockIdx.y;
    int swz = (lm & 7) << 3;                 // element-index XOR swizzle (16B blocks)

    // Q fragments (B-operand, rows=q): lane lm = q, c = ks*32 + lk*8
    bf16x8 qa[2];
    {
        const __bf16* qrow = &qT[((size_t)(n * LSP + q0 + lm)) * 64 + lk * 8];
        qa[0] = *reinterpret_cast<const bf16x8*>(qrow);
        qa[1] = *reinterpret_cast<const bf16x8*>(qrow + 32);
    }

    const __bf16* kbase = kpT + (size_t)n * LK * 64;
    const __bf16* vbase = vp + (size_t)n * CVo * LK;

    f32x4 accO[16] = {};
    float m = -1e30f, l = 0.0f;

    for (int kt = 0; kt < 13; kt++) {
        int kb = kt * 64;
        bool last = (kb == 768);             // only k 768..783 valid
        int nkg = last ? 1 : 4;
        // ---- S^T: accS[kg] = K[16k x 64c] x Q -> D[k][q], lane: q=lm, k=kb+kg*16+lk*4+r
        f32x4 accS[4] = {};
        #pragma unroll
        for (int kg = 0; kg < 4; kg++) {
            if (kg < nkg) {
                #pragma unroll
                for (int ks = 0; ks < 2; ks++) {
                    bf16x8 kf = *reinterpret_cast<const bf16x8*>(
                        &kbase[((size_t)(kb + kg * 16 + lm)) * 64 + ks * 32 + lk * 8]);
                    accS[kg] = __builtin_amdgcn_mfma_f32_16x16x32_bf16(kf, qa[ks], accS[kg], 0, 0, 0);
                }
            }
        }
        // ---- tile max over k (in-lane + lk-group reduce) ----
        float v = -1e30f;
        #pragma unroll
        for (int kg = 0; kg < 4; kg++)
            if (kg < nkg)
                #pragma unroll
                for (int r = 0; r < 4; r++) v = fmaxf(v, accS[kg][r]);
        v = fmaxf(v, __shfl_xor(v, 16));
        v = fmaxf(v, __shfl_xor(v, 32));
        // ---- T13 defer-max: rescale only when max grew > 8 ----
        float mn = fmaxf(m, v);
        if (__any(mn - m > 8.0f)) {
            float scale = __expf(m - mn);
            m = mn;
            l *= scale;
            #pragma unroll
            for (int mi = 0; mi < 16; mi++)
                #pragma unroll
                for (int r = 0; r < 4; r++) accO[mi][r] *= scale;
        }
        // ---- P = exp(S - m), row-sum, store to swizzled LDS ----
        float lt = 0.0f;
        #pragma unroll
        for (int kg = 0; kg < 4; kg++) {
            bf16x4 pw;
            if (kg < nkg) {
                #pragma unroll
                for (int r = 0; r < 4; r++) {
                    float p = __expf(accS[kg][r] - m);
                    lt += p;
                    pw[r] = (__bf16)p;
                }
            } else {
                pw[0] = (__bf16)0.f; pw[1] = (__bf16)0.f; pw[2] = (__bf16)0.f; pw[3] = (__bf16)0.f;
            }
            if (kg < 2 || !last)   // kg>=2 region never read on last tile
                *reinterpret_cast<bf16x4*>(&Ps[lm * 64 + ((kg * 16 + lk * 4) ^ swz)]) = pw;
        }
        lt += __shfl_xor(lt, 16);
        lt += __shfl_xor(lt, 32);
        l += lt;
        // ---- PV: accO[mi] (cv tile mi) += V[cv][k] x P[q][k] ----
        int nks = last ? 1 : 2;
        #pragma unroll
        for (int ks = 0; ks < 2; ks++) {
            if (ks < nks) {
                bf16x8 pf = *reinterpret_cast<const bf16x8*>(
                    &Ps[lm * 64 + ((ks * 32 + lk * 8) ^ swz)]);
                const __bf16* vk = &vbase[(size_t)lm * LK + kb + ks * 32 + lk * 8];
                #pragma unroll
                for (int mi = 0; mi < 16; mi++) {
                    bf16x8 vf = *reinterpret_cast<const bf16x8*>(&vk[(size_t)(mi * 16) * LK]);
                    accO[mi] = __builtin_amdgcn_mfma_f32_16x16x32_bf16(vf, pf, accO[mi], 0, 0, 0);
                }
            }
        }
    }
    // ---- finalize: lane stores q=q0+lm, cv = mi*16 + lk*4 + r ----
    float inv = 1.0f / l;
    __bf16* orow = &attT[((size_t)(n * LSP + q0 + lm)) * CVo + lk * 4];
    #pragma unroll
    for (int mi = 0; mi < 16; mi++) {
        bf16x4 o;
        o[0] = (__bf16)(accO[mi][0] * inv); o[1] = (__bf16)(accO[mi][1] * inv);
        o[2] = (__bf16)(accO[mi][2] * inv); o[3] = (__bf16)(accO[mi][3] * inv);
        *reinterpret_cast<bf16x4*>(&orow[mi * 16]) = o;
    }
}

// ---------------------------------------------------------------------------
// K6: Z MFMA GEMM + residual. A=attT(p rows), B=Wz(c rows) -> float4 epilogue.
// ---------------------------------------------------------------------------
__global__ __launch_bounds__(256) void z_gemm(const __bf16* __restrict__ Wzb,
                                              const __bf16* __restrict__ attT,
                                              const float* __restrict__ x,
                                              const float* __restrict__ yp,
                                              float* __restrict__ out)
{
    __shared__ __attribute__((aligned(16))) __bf16 As[128 * LDT];
    __shared__ __attribute__((aligned(16))) __bf16 Bs[128 * LDT];
    int t = threadIdx.x;
    int p0 = blockIdx.x * 128;
    int c0 = blockIdx.y * 128;
    int n  = blockIdx.z;
    int lane = t & 63, wid = t >> 6;
    int wm = wid >> 1, wn = wid & 1;
    int lm = lane & 15, lk = lane >> 4;

    f32x4 acc[4][4] = {};

    for (int kb = 0; kb < CVo; kb += 32) {
        #pragma unroll
        for (int i = 0; i < 2; i++) {
            int idx = i * 2048 + t * 8;
            int r = idx >> 5, k8 = idx & 31;
            *reinterpret_cast<uint4*>(&As[r * LDT + k8]) =
                *reinterpret_cast<const uint4*>(&attT[((size_t)(n * LSP + p0 + r)) * CVo + kb + k8]);
            *reinterpret_cast<uint4*>(&Bs[r * LDT + k8]) =
                *reinterpret_cast<const uint4*>(&Wzb[(size_t)(c0 + r) * CVo + kb + k8]);
        }
        __syncthreads();
        bf16x8 a[4], b[4];
        #pragma unroll
        for (int mi = 0; mi < 4; mi++)
            a[mi] = *reinterpret_cast<const bf16x8*>(&As[(wm * 64 + mi * 16 + lm) * LDT + lk * 8]);
        #pragma unroll
        for (int ni = 0; ni < 4; ni++)
            b[ni] = *reinterpret_cast<const bf16x8*>(&Bs[(wn * 64 + ni * 16 + lm) * LDT + lk * 8]);
        #pragma unroll
        for (int mi = 0; mi < 4; mi++)
            #pragma unroll
            for (int ni = 0; ni < 4; ni++)
                acc[mi][ni] = __builtin_amdgcn_mfma_f32_16x16x32_bf16(a[mi], b[ni], acc[mi][ni], 0, 0, 0);
        __syncthreads();
    }

    float yv = yp[0];
    #pragma unroll
    for (int mi = 0; mi < 4; mi++) {
        int p = p0 + wm * 64 + mi * 16 + lk * 4;
        #pragma unroll
        for (int ni = 0; ni < 4; ni++) {
            int c = c0 + wn * 64 + ni * 16 + lm;
            size_t o = ((size_t)(n * CIN + c)) * LSP + p;
            const float4 xv = *reinterpret_cast<const float4*>(&x[o]);
            float4 ov;
            ov.x = yv * acc[mi][ni][0] + xv.x;
            ov.y = yv * acc[mi][ni][1] + xv.y;
            ov.z = yv * acc[mi][ni][2] + xv.z;
            ov.w = yv * acc[mi][ni][3] + xv.w;
            *reinterpret_cast<float4*>(&out[o]) = ov;
        }
    }
}

// ---------------------------------------------------------------------------
// Workspace layout (bf16 elems, 2 B each). Total 34.8 MB.
//   kT    [4][6272][64]  @ 0           (1,605,632)
//   vconv [4][256][6272] @ 1,605,632   (6,422,528)
//   qT    [4][6272][64]  @ 8,028,160   (1,605,632)
//   kpT   [4][784][64]   @ 9,633,792   (  200,704)
//   vp    [4][256][784]  @ 9,834,496   (  802,816)
//   attT  [4][6272][256] @ 10,637,312  (6,422,528)
//   Wqkv  [384][512]     @ 17,059,840  (  196,608)
//   Wzb   [512][256]     @ 17,256,448  (  131,072)
// ---------------------------------------------------------------------------
extern "C" void kernel_launch(void* const* d_in, const int* in_sizes, int n_in,
                              void* d_out, int out_size, void* d_ws, size_t ws_size,
                              hipStream_t stream)
{
    const float* x  = (const float*)d_in[0];
    const float* Wq = (const float*)d_in[1];
    const float* Wk = (const float*)d_in[2];
    const float* Wv = (const float*)d_in[3];
    const float* Wz = (const float*)d_in[4];
    const float* y  = (const float*)d_in[5];
    float* out = (float*)d_out;
    __bf16* ws = (__bf16*)d_ws;

    __bf16* kT    = ws;
    __bf16* vconv = ws + (size_t)1605632;
    __bf16* qT    = ws + (size_t)8028160;
    __bf16* kpT   = ws + (size_t)9633792;
    __bf16* vp    = ws + (size_t)9834496;
    __bf16* attT  = ws + (size_t)10637312;
    __bf16* Wqkv  = ws + (size_t)17059840;
    __bf16* Wzb   = ws + (size_t)17256448;

    wprep_kernel  <<<dim3(768), 256, 0, stream>>>(Wq, Wk, Wv, Wz, Wqkv, Wzb);
    qkv_gemm      <<<dim3(49, 3, 4), 256, 0, stream>>>(Wqkv, x, qT, kT, vconv);
    poolk_kernel  <<<dim3(784), 256, 0, stream>>>(kT, kpT);
    poolv_kernel  <<<dim3(3136), 256, 0, stream>>>(vconv, vp);
    flash2_kernel <<<dim3(392, 4), 64, 0, stream>>>(qT, kpT, vp, attT);
    z_gemm        <<<dim3(49, 4, 4), 256, 0, stream>>>(Wzb, attT, x, y, out);
}

// Round 5
// 216.115 us; speedup vs baseline: 1.3838x; 1.3838x over previous
//
#include <hip/hip_runtime.h>
#include <hip/hip_bf16.h>

// Problem constants
#define LSP  6272   // 8*28*28 spatial
#define LK   784    // 4*14*14 pooled spatial
#define CIN  512
#define CQo  64
#define CVo  256
#define NB   4

typedef __bf16  bf16x8 __attribute__((ext_vector_type(8)));
typedef __bf16  bf16x4 __attribute__((ext_vector_type(4)));
typedef float   f32x4  __attribute__((ext_vector_type(4)));

#define LDT  40   // padded LDS row (bf16 elems): 80 B = 16*5, keeps b128 aligned

// ---------------------------------------------------------------------------
// K0b: weight prep. Wqkv bf16 [384][512]; Wzb bf16 [512][256]
// ---------------------------------------------------------------------------
__global__ void wprep_kernel(const float* __restrict__ Wq, const float* __restrict__ Wk,
                             const float* __restrict__ Wv, const float* __restrict__ Wz,
                             __bf16* __restrict__ Wqkv, __bf16* __restrict__ Wzb)
{
    int idx = blockIdx.x * 256 + threadIdx.x;
    if (idx < 384 * 512) {
        int o = idx >> 9;
        float v = (o < 64) ? Wq[idx] : (o < 128) ? Wk[idx - 64 * 512] : Wv[idx - 128 * 512];
        Wqkv[idx] = (__bf16)v;
    }
    if (idx < 512 * 256) Wzb[idx] = (__bf16)Wz[idx];
}

// ---------------------------------------------------------------------------
// K1: QKV MFMA GEMM with fused x transpose+convert (validated round 4).
// ---------------------------------------------------------------------------
__global__ __launch_bounds__(256) void qkv_gemm(const __bf16* __restrict__ Wqkv,
                                                const float* __restrict__ x,
                                                __bf16* __restrict__ qT,
                                                __bf16* __restrict__ kT,
                                                __bf16* __restrict__ vconv)
{
    __shared__ __attribute__((aligned(16))) __bf16 As[128 * LDT];
    __shared__ __attribute__((aligned(16))) __bf16 Bs[128 * LDT];
    int t = threadIdx.x;
    int p0 = blockIdx.x * 128;
    int m0 = blockIdx.y * 128;
    int n  = blockIdx.z;
    int lane = t & 63, wid = t >> 6;
    int wm = wid >> 1, wn = wid & 1;
    int lm = lane & 15, lk = lane >> 4;
    int cS = t >> 3, pqS = t & 7;

    f32x4 acc[4][4] = {};

    for (int kb = 0; kb < CIN; kb += 32) {
        #pragma unroll
        for (int i = 0; i < 2; i++) {
            int idx = i * 2048 + t * 8;
            int r = idx >> 5, k8 = idx & 31;
            *reinterpret_cast<uint4*>(&As[r * LDT + k8]) =
                *reinterpret_cast<const uint4*>(&Wqkv[(size_t)(m0 + r) * CIN + kb + k8]);
        }
        #pragma unroll
        for (int i = 0; i < 4; i++) {
            int p = i * 32 + pqS * 4;
            const float4 v = *reinterpret_cast<const float4*>(
                &x[((size_t)(n * CIN + kb + cS)) * LSP + p0 + p]);
            int csw = cS ^ ((pqS & 3) << 3);
            Bs[(p + 0) * LDT + csw] = (__bf16)v.x;
            Bs[(p + 1) * LDT + csw] = (__bf16)v.y;
            Bs[(p + 2) * LDT + csw] = (__bf16)v.z;
            Bs[(p + 3) * LDT + csw] = (__bf16)v.w;
        }
        __syncthreads();
        if (m0 == 0) {
            bf16x8 a[4], b[4];
            #pragma unroll
            for (int mi = 0; mi < 4; mi++)
                a[mi] = *reinterpret_cast<const bf16x8*>(&As[(wm * 64 + mi * 16 + lm) * LDT + lk * 8]);
            #pragma unroll
            for (int ni = 0; ni < 4; ni++) {
                int row = wn * 64 + ni * 16 + lm;
                b[ni] = *reinterpret_cast<const bf16x8*>(
                    &Bs[row * LDT + ((lk * 8) ^ (((row >> 2) & 3) << 3))]);
            }
            #pragma unroll
            for (int mi = 0; mi < 4; mi++)
                #pragma unroll
                for (int ni = 0; ni < 4; ni++)
                    acc[mi][ni] = __builtin_amdgcn_mfma_f32_16x16x32_bf16(a[mi], b[ni], acc[mi][ni], 0, 0, 0);
        } else {
            bf16x8 a[4], b[4];
            #pragma unroll
            for (int mi = 0; mi < 4; mi++) {
                int row = wn * 64 + mi * 16 + lm;
                a[mi] = *reinterpret_cast<const bf16x8*>(
                    &Bs[row * LDT + ((lk * 8) ^ (((row >> 2) & 3) << 3))]);
            }
            #pragma unroll
            for (int ni = 0; ni < 4; ni++)
                b[ni] = *reinterpret_cast<const bf16x8*>(&As[(wm * 64 + ni * 16 + lm) * LDT + lk * 8]);
            #pragma unroll
            for (int mi = 0; mi < 4; mi++)
                #pragma unroll
                for (int ni = 0; ni < 4; ni++)
                    acc[mi][ni] = __builtin_amdgcn_mfma_f32_16x16x32_bf16(a[mi], b[ni], acc[mi][ni], 0, 0, 0);
        }
        __syncthreads();
    }

    if (m0 == 0) {
        #pragma unroll
        for (int mi = 0; mi < 4; mi++) {
            int mloc = wm * 64 + mi * 16 + lk * 4;
            #pragma unroll
            for (int ni = 0; ni < 4; ni++) {
                int p = p0 + wn * 64 + ni * 16 + lm;
                bf16x4 o;
                o[0] = (__bf16)acc[mi][ni][0]; o[1] = (__bf16)acc[mi][ni][1];
                o[2] = (__bf16)acc[mi][ni][2]; o[3] = (__bf16)acc[mi][ni][3];
                if (mloc < 64)
                    *reinterpret_cast<bf16x4*>(&qT[((size_t)(n * LSP + p)) * 64 + mloc]) = o;
                else
                    *reinterpret_cast<bf16x4*>(&kT[((size_t)(n * LSP + p)) * 64 + (mloc - 64)]) = o;
            }
        }
    } else {
        #pragma unroll
        for (int mi = 0; mi < 4; mi++) {
            int p = p0 + wn * 64 + mi * 16 + lk * 4;
            #pragma unroll
            for (int ni = 0; ni < 4; ni++) {
                int cv = (m0 - 128) + wm * 64 + ni * 16 + lm;
                bf16x4 o;
                o[0] = (__bf16)acc[mi][ni][0]; o[1] = (__bf16)acc[mi][ni][1];
                o[2] = (__bf16)acc[mi][ni][2]; o[3] = (__bf16)acc[mi][ni][3];
                *reinterpret_cast<bf16x4*>(&vconv[((size_t)(n * CVo + cv)) * LSP + p]) = o;
            }
        }
    }
}

// ---------------------------------------------------------------------------
// K2a: pool kT [n][p][64] -> kpT [n][784][64]
// ---------------------------------------------------------------------------
__global__ __launch_bounds__(256) void poolk_kernel(const __bf16* __restrict__ kT,
                                                    __bf16* __restrict__ kpT)
{
    int wid = threadIdx.x >> 6, lane = threadIdx.x & 63;
    int row = blockIdx.x * 4 + wid;
    int n = row / LK, pk = row % LK;
    int tp = pk / 196, rem = pk % 196, hp = rem / 14, wp = rem % 14;
    const __bf16* b = kT + ((size_t)n * LSP + tp * 2 * 784 + hp * 2 * 28 + wp * 2) * 64 + lane;
    float m =        (float)b[0];
    m = fmaxf(m, (float)b[64]);
    m = fmaxf(m, (float)b[28 * 64]);
    m = fmaxf(m, (float)b[29 * 64]);
    m = fmaxf(m, (float)b[784 * 64]);
    m = fmaxf(m, (float)b[785 * 64]);
    m = fmaxf(m, (float)b[812 * 64]);
    m = fmaxf(m, (float)b[813 * 64]);
    kpT[(size_t)row * 64 + lane] = (__bf16)m;
}

// ---------------------------------------------------------------------------
// K2b: pool vconv [n][cv][p] -> vp [n][cv][784]
// ---------------------------------------------------------------------------
__global__ void poolv_kernel(const __bf16* __restrict__ vconv, __bf16* __restrict__ vp)
{
    int id = blockIdx.x * 256 + threadIdx.x;
    if (id >= NB * CVo * LK) return;
    int nc = id / LK, pk = id % LK;
    int tp = pk / 196, rem = pk % 196, hp = rem / 14, wp = rem % 14;
    const __bf16* b = vconv + (size_t)nc * LSP + tp * 2 * 784 + hp * 2 * 28 + wp * 2;
    float m =        (float)b[0];
    m = fmaxf(m, (float)b[1]);   m = fmaxf(m, (float)b[28]);  m = fmaxf(m, (float)b[29]);
    m = fmaxf(m, (float)b[784]); m = fmaxf(m, (float)b[785]); m = fmaxf(m, (float)b[812]); m = fmaxf(m, (float)b[813]);
    vp[id] = (__bf16)m;
}

// ---------------------------------------------------------------------------
// K3: flash3 — 8 waves, QB=128 q rows/block, grid 49x4 = 196 blocks (1 round).
// Per k-tile(64): K dbuf in LDS (reg-staged ds_write_b128, XOR swizzle);
// V wave-partitioned (wave w owns cv w*32..w*32+31), frags prefetched
// global->reg one tile ahead; S^T = mfma(K,Q) -> in-lane online softmax
// (defer-max, thr=8); P through 16KB swizzled LDS; 2 barriers/tile.
// ---------------------------------------------------------------------------
__global__ __launch_bounds__(512) void flash3_kernel(
    const __bf16* __restrict__ qT, const __bf16* __restrict__ kpT,
    const __bf16* __restrict__ vp, __bf16* __restrict__ attT)
{
    __shared__ __attribute__((aligned(16))) __bf16 Kbuf[2][64 * 64]; // [k][c] swizzled
    __shared__ __attribute__((aligned(16))) __bf16 Ps[128 * 64];     // [q][k] swizzled
    __shared__ float scs[128];
    __shared__ float invl[128];

    int t = threadIdx.x;
    int lane = t & 63, w = t >> 6;           // 8 waves
    int lm = lane & 15, lk = lane >> 4;
    int q0 = blockIdx.x * 128;
    int n  = blockIdx.y;
    int swz = (lm & 7) << 3;                 // element XOR swizzle (16B granules)

    const __bf16* kbase = kpT + (size_t)n * LK * 64;
    const __bf16* vbase = vp  + (size_t)n * CVo * LK;

    // Q regs: q row = q0 + w*16 + lm
    bf16x8 qa[2];
    {
        const __bf16* qrow = &qT[((size_t)(n * LSP + q0 + w * 16 + lm)) * 64 + lk * 8];
        qa[0] = *reinterpret_cast<const bf16x8*>(qrow);
        qa[1] = *reinterpret_cast<const bf16x8*>(qrow + 32);
    }

    // K staging: thread t handles 16B chunk: row kr = t>>3, chunk kc = t&7
    int kr = t >> 3, kc = t & 7;
    int kds = kr * 64 + ((kc * 8) ^ ((kr & 7) << 3));
    const __bf16* kgsrc = &kbase[(size_t)kr * 64 + kc * 8];

    // V frag sources: wave w rows cv = w*32 + mi*16 + lm, elems ks*32+lk*8
    const __bf16* vsrc[2][2];
    #pragma unroll
    for (int mi = 0; mi < 2; mi++)
        #pragma unroll
        for (int ks = 0; ks < 2; ks++)
            vsrc[mi][ks] = &vbase[(size_t)(w * 32 + mi * 16 + lm) * LK + ks * 32 + lk * 8];

    uint4 kreg;
    bf16x8 vcur[2][2], vnxt[2][2];

    // prologue: tile 0
    kreg = *reinterpret_cast<const uint4*>(kgsrc);
    #pragma unroll
    for (int mi = 0; mi < 2; mi++)
        #pragma unroll
        for (int ks = 0; ks < 2; ks++)
            vcur[mi][ks] = *reinterpret_cast<const bf16x8*>(vsrc[mi][ks]);
    *reinterpret_cast<uint4*>(&Kbuf[0][kds]) = kreg;
    __syncthreads();

    f32x4 accO[2][8] = {};
    float m = -1e30f, l = 0.0f;
    int qrow = w * 16 + lm;

    for (int kt = 0; kt < 13; kt++) {
        int cur = kt & 1;
        bool have_next = (kt < 12);
        bool lastT = (kt == 12);
        if (have_next) {
            size_t off = (size_t)(kt + 1) * 64;
            kreg = *reinterpret_cast<const uint4*>(kgsrc + off * 64);
            #pragma unroll
            for (int mi = 0; mi < 2; mi++)
                #pragma unroll
                for (int ks = 0; ks < 2; ks++)
                    vnxt[mi][ks] = *reinterpret_cast<const bf16x8*>(vsrc[mi][ks] + off);
        }
        // ---- S phase: accS[kg], k = kt*64 + kg*16 + lk*4 + r, q col = lm ----
        f32x4 accS[4] = {};
        #pragma unroll
        for (int kg = 0; kg < 4; kg++) {
            if (!lastT || kg == 0) {
                #pragma unroll
                for (int ks = 0; ks < 2; ks++) {
                    bf16x8 kf = *reinterpret_cast<const bf16x8*>(
                        &Kbuf[cur][(kg * 16 + lm) * 64 + ((ks * 32 + lk * 8) ^ swz)]);
                    accS[kg] = __builtin_amdgcn_mfma_f32_16x16x32_bf16(kf, qa[ks], accS[kg], 0, 0, 0);
                }
            } else {
                accS[kg][0] = -1e30f; accS[kg][1] = -1e30f;
                accS[kg][2] = -1e30f; accS[kg][3] = -1e30f;
            }
        }
        // ---- online softmax for q = qrow (in-lane + lk-reduce) ----
        float v = -1e30f;
        #pragma unroll
        for (int kg = 0; kg < 4; kg++)
            #pragma unroll
            for (int r = 0; r < 4; r++) v = fmaxf(v, accS[kg][r]);
        v = fmaxf(v, __shfl_xor(v, 16));
        v = fmaxf(v, __shfl_xor(v, 32));
        float sc_out = 1.0f;
        if (__any(v - m > 8.0f)) {           // T13 defer-max
            float mn = fmaxf(m, v);
            sc_out = __expf(m - mn);
            l *= sc_out;
            m = mn;
        }
        float lt = 0.0f;
        #pragma unroll
        for (int kg = 0; kg < 4; kg++) {
            bf16x4 pw;
            #pragma unroll
            for (int r = 0; r < 4; r++) {
                float p = __expf(accS[kg][r] - m);
                lt += p;
                pw[r] = (__bf16)p;
            }
            *reinterpret_cast<bf16x4*>(&Ps[qrow * 64 + ((kg * 16 + lk * 4) ^ swz)]) = pw;
        }
        lt += __shfl_xor(lt, 16);
        lt += __shfl_xor(lt, 32);
        l += lt;
        if (lk == 0) scs[qrow] = sc_out;
        __syncthreads();
        // ---- O rescale (block-uniform skip when all scales == 1) ----
        float s[8];
        #pragma unroll
        for (int ni = 0; ni < 8; ni++) s[ni] = scs[ni * 16 + lm];
        bool need = false;
        #pragma unroll
        for (int ni = 0; ni < 8; ni++) need = need || (s[ni] != 1.0f);
        if (__any(need)) {
            #pragma unroll
            for (int mi = 0; mi < 2; mi++)
                #pragma unroll
                for (int ni = 0; ni < 8; ni++)
                    #pragma unroll
                    for (int r = 0; r < 4; r++) accO[mi][ni][r] *= s[ni];
        }
        // ---- PV: accO[mi][ni] += V[cv] x P[q] ----
        #pragma unroll
        for (int ks = 0; ks < 2; ks++) {
            bf16x8 pf[8];
            #pragma unroll
            for (int ni = 0; ni < 8; ni++)
                pf[ni] = *reinterpret_cast<const bf16x8*>(
                    &Ps[(ni * 16 + lm) * 64 + ((ks * 32 + lk * 8) ^ swz)]);
            #pragma unroll
            for (int mi = 0; mi < 2; mi++)
                #pragma unroll
                for (int ni = 0; ni < 8; ni++)
                    accO[mi][ni] = __builtin_amdgcn_mfma_f32_16x16x32_bf16(
                        vcur[mi][ks], pf[ni], accO[mi][ni], 0, 0, 0);
        }
        if (have_next)
            *reinterpret_cast<uint4*>(&Kbuf[cur ^ 1][kds]) = kreg;
        __syncthreads();
        #pragma unroll
        for (int mi = 0; mi < 2; mi++)
            #pragma unroll
            for (int ks = 0; ks < 2; ks++)
                vcur[mi][ks] = vnxt[mi][ks];
    }
    // ---- finalize ----
    if (lk == 0) invl[qrow] = 1.0f / l;
    __syncthreads();
    #pragma unroll
    for (int ni = 0; ni < 8; ni++) {
        float inv = invl[ni * 16 + lm];
        __bf16* orow = &attT[((size_t)(n * LSP + q0 + ni * 16 + lm)) * CVo + w * 32 + lk * 4];
        #pragma unroll
        for (int mi = 0; mi < 2; mi++) {
            bf16x4 o;
            o[0] = (__bf16)(accO[mi][ni][0] * inv);
            o[1] = (__bf16)(accO[mi][ni][1] * inv);
            o[2] = (__bf16)(accO[mi][ni][2] * inv);
            o[3] = (__bf16)(accO[mi][ni][3] * inv);
            *reinterpret_cast<bf16x4*>(&orow[mi * 16]) = o;
        }
    }
}

// ---------------------------------------------------------------------------
// K6: Z MFMA GEMM + residual. A=attT(p rows), B=Wz(c rows) -> float4 epilogue.
// ---------------------------------------------------------------------------
__global__ __launch_bounds__(256) void z_gemm(const __bf16* __restrict__ Wzb,
                                              const __bf16* __restrict__ attT,
                                              const float* __restrict__ x,
                                              const float* __restrict__ yp,
                                              float* __restrict__ out)
{
    __shared__ __attribute__((aligned(16))) __bf16 As[128 * LDT];
    __shared__ __attribute__((aligned(16))) __bf16 Bs[128 * LDT];
    int t = threadIdx.x;
    int p0 = blockIdx.x * 128;
    int c0 = blockIdx.y * 128;
    int n  = blockIdx.z;
    int lane = t & 63, wid = t >> 6;
    int wm = wid >> 1, wn = wid & 1;
    int lm = lane & 15, lk = lane >> 4;

    f32x4 acc[4][4] = {};

    for (int kb = 0; kb < CVo; kb += 32) {
        #pragma unroll
        for (int i = 0; i < 2; i++) {
            int idx = i * 2048 + t * 8;
            int r = idx >> 5, k8 = idx & 31;
            *reinterpret_cast<uint4*>(&As[r * LDT + k8]) =
                *reinterpret_cast<const uint4*>(&attT[((size_t)(n * LSP + p0 + r)) * CVo + kb + k8]);
            *reinterpret_cast<uint4*>(&Bs[r * LDT + k8]) =
                *reinterpret_cast<const uint4*>(&Wzb[(size_t)(c0 + r) * CVo + kb + k8]);
        }
        __syncthreads();
        bf16x8 a[4], b[4];
        #pragma unroll
        for (int mi = 0; mi < 4; mi++)
            a[mi] = *reinterpret_cast<const bf16x8*>(&As[(wm * 64 + mi * 16 + lm) * LDT + lk * 8]);
        #pragma unroll
        for (int ni = 0; ni < 4; ni++)
            b[ni] = *reinterpret_cast<const bf16x8*>(&Bs[(wn * 64 + ni * 16 + lm) * LDT + lk * 8]);
        #pragma unroll
        for (int mi = 0; mi < 4; mi++)
            #pragma unroll
            for (int ni = 0; ni < 4; ni++)
                acc[mi][ni] = __builtin_amdgcn_mfma_f32_16x16x32_bf16(a[mi], b[ni], acc[mi][ni], 0, 0, 0);
        __syncthreads();
    }

    float yv = yp[0];
    #pragma unroll
    for (int mi = 0; mi < 4; mi++) {
        int p = p0 + wm * 64 + mi * 16 + lk * 4;
        #pragma unroll
        for (int ni = 0; ni < 4; ni++) {
            int c = c0 + wn * 64 + ni * 16 + lm;
            size_t o = ((size_t)(n * CIN + c)) * LSP + p;
            const float4 xv = *reinterpret_cast<const float4*>(&x[o]);
            float4 ov;
            ov.x = yv * acc[mi][ni][0] + xv.x;
            ov.y = yv * acc[mi][ni][1] + xv.y;
            ov.z = yv * acc[mi][ni][2] + xv.z;
            ov.w = yv * acc[mi][ni][3] + xv.w;
            *reinterpret_cast<float4*>(&out[o]) = ov;
        }
    }
}

// ---------------------------------------------------------------------------
// Workspace layout (bf16 elems, 2 B each). Total 34.8 MB.
//   kT    [4][6272][64]  @ 0           (1,605,632)
//   vconv [4][256][6272] @ 1,605,632   (6,422,528)
//   qT    [4][6272][64]  @ 8,028,160   (1,605,632)
//   kpT   [4][784][64]   @ 9,633,792   (  200,704)
//   vp    [4][256][784]  @ 9,834,496   (  802,816)
//   attT  [4][6272][256] @ 10,637,312  (6,422,528)
//   Wqkv  [384][512]     @ 17,059,840  (  196,608)
//   Wzb   [512][256]     @ 17,256,448  (  131,072)
// ---------------------------------------------------------------------------
extern "C" void kernel_launch(void* const* d_in, const int* in_sizes, int n_in,
                              void* d_out, int out_size, void* d_ws, size_t ws_size,
                              hipStream_t stream)
{
    const float* x  = (const float*)d_in[0];
    const float* Wq = (const float*)d_in[1];
    const float* Wk = (const float*)d_in[2];
    const float* Wv = (const float*)d_in[3];
    const float* Wz = (const float*)d_in[4];
    const float* y  = (const float*)d_in[5];
    float* out = (float*)d_out;
    __bf16* ws = (__bf16*)d_ws;

    __bf16* kT    = ws;
    __bf16* vconv = ws + (size_t)1605632;
    __bf16* qT    = ws + (size_t)8028160;
    __bf16* kpT   = ws + (size_t)9633792;
    __bf16* vp    = ws + (size_t)9834496;
    __bf16* attT  = ws + (size_t)10637312;
    __bf16* Wqkv  = ws + (size_t)17059840;
    __bf16* Wzb   = ws + (size_t)17256448;

    wprep_kernel  <<<dim3(768), 256, 0, stream>>>(Wq, Wk, Wv, Wz, Wqkv, Wzb);
    qkv_gemm      <<<dim3(49, 3, 4), 256, 0, stream>>>(Wqkv, x, qT, kT, vconv);
    poolk_kernel  <<<dim3(784), 256, 0, stream>>>(kT, kpT);
    poolv_kernel  <<<dim3(3136), 256, 0, stream>>>(vconv, vp);
    flash3_kernel <<<dim3(49, 4), 512, 0, stream>>>(qT, kpT, vp, attT);
    z_gemm        <<<dim3(49, 4, 4), 256, 0, stream>>>(Wzb, attT, x, y, out);
}

// Round 6
// 210.768 us; speedup vs baseline: 1.4189x; 1.0254x over previous
//
#include <hip/hip_runtime.h>
#include <hip/hip_bf16.h>

// Problem constants
#define LSP  6272   // 8*28*28 spatial
#define LK   784    // 4*14*14 pooled spatial
#define CIN  512
#define CQo  64
#define CVo  256
#define NB   4

typedef __bf16  bf16x8 __attribute__((ext_vector_type(8)));
typedef __bf16  bf16x4 __attribute__((ext_vector_type(4)));
typedef float   f32x4  __attribute__((ext_vector_type(4)));

#define LDT  40   // padded LDS row (bf16 elems): 80 B — 2-way on b128 reads (free)

// ---------------------------------------------------------------------------
// K0: transpose+convert x [n][c][p] fp32 -> xT [n][p][c] bf16  (~13 us, BW-bound)
// ---------------------------------------------------------------------------
__global__ __launch_bounds__(256) void xt_kernel(const float* __restrict__ x,
                                                 __bf16* __restrict__ xT)
{
    __shared__ __attribute__((aligned(16))) __bf16 tile[64][68];
    int t = threadIdx.x;
    int p0 = blockIdx.x * 64, c0 = blockIdx.y * 64, n = blockIdx.z;
    #pragma unroll
    for (int i = 0; i < 4; i++) {
        int idx = i * 256 + t;
        int c = idx >> 4, p4 = (idx & 15) * 4;
        const float4 v = *reinterpret_cast<const float4*>(
            &x[((size_t)(n * CIN + c0 + c)) * LSP + p0 + p4]);
        tile[p4 + 0][c] = (__bf16)v.x;
        tile[p4 + 1][c] = (__bf16)v.y;
        tile[p4 + 2][c] = (__bf16)v.z;
        tile[p4 + 3][c] = (__bf16)v.w;
    }
    __syncthreads();
    #pragma unroll
    for (int i = 0; i < 4; i++) {
        int idx = i * 256 + t;
        int p = idx >> 4, c4 = (idx & 15) * 4;
        bf16x4 o;
        o[0] = tile[p][c4 + 0]; o[1] = tile[p][c4 + 1];
        o[2] = tile[p][c4 + 2]; o[3] = tile[p][c4 + 3];
        *reinterpret_cast<bf16x4*>(&xT[((size_t)(n * LSP + p0 + p)) * CIN + c0 + c4]) = o;
    }
}

// ---------------------------------------------------------------------------
// K0b: weight prep. Wqkv bf16 [384][512]; Wzb bf16 [512][256]
// ---------------------------------------------------------------------------
__global__ void wprep_kernel(const float* __restrict__ Wq, const float* __restrict__ Wk,
                             const float* __restrict__ Wv, const float* __restrict__ Wz,
                             __bf16* __restrict__ Wqkv, __bf16* __restrict__ Wzb)
{
    int idx = blockIdx.x * 256 + threadIdx.x;
    if (idx < 384 * 512) {
        int o = idx >> 9;
        float v = (o < 64) ? Wq[idx] : (o < 128) ? Wk[idx - 64 * 512] : Wv[idx - 128 * 512];
        Wqkv[idx] = (__bf16)v;
    }
    if (idx < 512 * 256) Wzb[idx] = (__bf16)Wz[idx];
}

// ---------------------------------------------------------------------------
// K1: QKV MFMA GEMM, bf16 xT input, register-double-buffered staging.
// Per k-step: issue next-step global loads -> MFMA on buf[cur] -> LDS-write
// next into buf[cur^1] -> 1 barrier.
// m0==0 (q,k): A=W, B=xT -> D[o][p], store qT/kT[p][o] bf16x4 (along o).
// m0>0  (v):   A=xT, B=W -> D[p][cv], store vconv[cv][p] bf16x4 (along p).
// ---------------------------------------------------------------------------
__global__ __launch_bounds__(256) void qkv_gemm(const __bf16* __restrict__ Wqkv,
                                                const __bf16* __restrict__ xT,
                                                __bf16* __restrict__ qT,
                                                __bf16* __restrict__ kT,
                                                __bf16* __restrict__ vconv)
{
    __shared__ __attribute__((aligned(16))) __bf16 As[2][128 * LDT];
    __shared__ __attribute__((aligned(16))) __bf16 Bs[2][128 * LDT];
    int t = threadIdx.x;
    int p0 = blockIdx.x * 128;
    int m0 = blockIdx.y * 128;
    int n  = blockIdx.z;
    int lane = t & 63, wid = t >> 6;
    int wm = wid >> 1, wn = wid & 1;
    int lm = lane & 15, lk = lane >> 4;

    // staging: thread t covers rows r = t>>2 and r+64, 16B chunk (t&3)*8
    const __bf16* wsrc = &Wqkv[(size_t)(m0 + (t >> 2)) * CIN + (t & 3) * 8];
    const __bf16* xsrc = &xT[((size_t)(n * LSP + p0 + (t >> 2))) * CIN + (t & 3) * 8];
    int dsoff = (t >> 2) * LDT + (t & 3) * 8;

    uint4 wa[2], xb[2];
    f32x4 acc[4][4] = {};

    // prologue: k-step 0
    wa[0] = *reinterpret_cast<const uint4*>(wsrc);
    wa[1] = *reinterpret_cast<const uint4*>(wsrc + 64 * CIN);
    xb[0] = *reinterpret_cast<const uint4*>(xsrc);
    xb[1] = *reinterpret_cast<const uint4*>(xsrc + 64 * CIN);
    *reinterpret_cast<uint4*>(&As[0][dsoff]) = wa[0];
    *reinterpret_cast<uint4*>(&As[0][dsoff + 64 * LDT]) = wa[1];
    *reinterpret_cast<uint4*>(&Bs[0][dsoff]) = xb[0];
    *reinterpret_cast<uint4*>(&Bs[0][dsoff + 64 * LDT]) = xb[1];
    __syncthreads();

    for (int kt = 0; kt < 16; kt++) {
        int cur = kt & 1;
        if (kt < 15) {
            int ko = (kt + 1) * 32;
            wa[0] = *reinterpret_cast<const uint4*>(wsrc + ko);
            wa[1] = *reinterpret_cast<const uint4*>(wsrc + 64 * CIN + ko);
            xb[0] = *reinterpret_cast<const uint4*>(xsrc + ko);
            xb[1] = *reinterpret_cast<const uint4*>(xsrc + 64 * CIN + ko);
        }
        bf16x8 a[4], b[4];
        if (m0 == 0) {
            #pragma unroll
            for (int mi = 0; mi < 4; mi++)
                a[mi] = *reinterpret_cast<const bf16x8*>(&As[cur][(wm * 64 + mi * 16 + lm) * LDT + lk * 8]);
            #pragma unroll
            for (int ni = 0; ni < 4; ni++)
                b[ni] = *reinterpret_cast<const bf16x8*>(&Bs[cur][(wn * 64 + ni * 16 + lm) * LDT + lk * 8]);
        } else {
            #pragma unroll
            for (int mi = 0; mi < 4; mi++)
                a[mi] = *reinterpret_cast<const bf16x8*>(&Bs[cur][(wn * 64 + mi * 16 + lm) * LDT + lk * 8]);
            #pragma unroll
            for (int ni = 0; ni < 4; ni++)
                b[ni] = *reinterpret_cast<const bf16x8*>(&As[cur][(wm * 64 + ni * 16 + lm) * LDT + lk * 8]);
        }
        #pragma unroll
        for (int mi = 0; mi < 4; mi++)
            #pragma unroll
            for (int ni = 0; ni < 4; ni++)
                acc[mi][ni] = __builtin_amdgcn_mfma_f32_16x16x32_bf16(a[mi], b[ni], acc[mi][ni], 0, 0, 0);
        if (kt < 15) {
            *reinterpret_cast<uint4*>(&As[cur ^ 1][dsoff]) = wa[0];
            *reinterpret_cast<uint4*>(&As[cur ^ 1][dsoff + 64 * LDT]) = wa[1];
            *reinterpret_cast<uint4*>(&Bs[cur ^ 1][dsoff]) = xb[0];
            *reinterpret_cast<uint4*>(&Bs[cur ^ 1][dsoff + 64 * LDT]) = xb[1];
        }
        __syncthreads();
    }

    if (m0 == 0) {
        #pragma unroll
        for (int mi = 0; mi < 4; mi++) {
            int mloc = wm * 64 + mi * 16 + lk * 4;
            #pragma unroll
            for (int ni = 0; ni < 4; ni++) {
                int p = p0 + wn * 64 + ni * 16 + lm;
                bf16x4 o;
                o[0] = (__bf16)acc[mi][ni][0]; o[1] = (__bf16)acc[mi][ni][1];
                o[2] = (__bf16)acc[mi][ni][2]; o[3] = (__bf16)acc[mi][ni][3];
                if (mloc < 64)
                    *reinterpret_cast<bf16x4*>(&qT[((size_t)(n * LSP + p)) * 64 + mloc]) = o;
                else
                    *reinterpret_cast<bf16x4*>(&kT[((size_t)(n * LSP + p)) * 64 + (mloc - 64)]) = o;
            }
        }
    } else {
        #pragma unroll
        for (int mi = 0; mi < 4; mi++) {
            int p = p0 + wn * 64 + mi * 16 + lk * 4;
            #pragma unroll
            for (int ni = 0; ni < 4; ni++) {
                int cv = (m0 - 128) + wm * 64 + ni * 16 + lm;
                bf16x4 o;
                o[0] = (__bf16)acc[mi][ni][0]; o[1] = (__bf16)acc[mi][ni][1];
                o[2] = (__bf16)acc[mi][ni][2]; o[3] = (__bf16)acc[mi][ni][3];
                *reinterpret_cast<bf16x4*>(&vconv[((size_t)(n * CVo + cv)) * LSP + p]) = o;
            }
        }
    }
}

// ---------------------------------------------------------------------------
// K2a: pool kT [n][p][64] -> kpT [n][784][64]
// ---------------------------------------------------------------------------
__global__ __launch_bounds__(256) void poolk_kernel(const __bf16* __restrict__ kT,
                                                    __bf16* __restrict__ kpT)
{
    int wid = threadIdx.x >> 6, lane = threadIdx.x & 63;
    int row = blockIdx.x * 4 + wid;
    int n = row / LK, pk = row % LK;
    int tp = pk / 196, rem = pk % 196, hp = rem / 14, wp = rem % 14;
    const __bf16* b = kT + ((size_t)n * LSP + tp * 2 * 784 + hp * 2 * 28 + wp * 2) * 64 + lane;
    float m =        (float)b[0];
    m = fmaxf(m, (float)b[64]);
    m = fmaxf(m, (float)b[28 * 64]);
    m = fmaxf(m, (float)b[29 * 64]);
    m = fmaxf(m, (float)b[784 * 64]);
    m = fmaxf(m, (float)b[785 * 64]);
    m = fmaxf(m, (float)b[812 * 64]);
    m = fmaxf(m, (float)b[813 * 64]);
    kpT[(size_t)row * 64 + lane] = (__bf16)m;
}

// ---------------------------------------------------------------------------
// K2b: pool vconv [n][cv][p] -> vp [n][cv][784]
// ---------------------------------------------------------------------------
__global__ void poolv_kernel(const __bf16* __restrict__ vconv, __bf16* __restrict__ vp)
{
    int id = blockIdx.x * 256 + threadIdx.x;
    if (id >= NB * CVo * LK) return;
    int nc = id / LK, pk = id % LK;
    int tp = pk / 196, rem = pk % 196, hp = rem / 14, wp = rem % 14;
    const __bf16* b = vconv + (size_t)nc * LSP + tp * 2 * 784 + hp * 2 * 28 + wp * 2;
    float m =        (float)b[0];
    m = fmaxf(m, (float)b[1]);   m = fmaxf(m, (float)b[28]);  m = fmaxf(m, (float)b[29]);
    m = fmaxf(m, (float)b[784]); m = fmaxf(m, (float)b[785]); m = fmaxf(m, (float)b[812]); m = fmaxf(m, (float)b[813]);
    vp[id] = (__bf16)m;
}

// ---------------------------------------------------------------------------
// K3: flash3 (validated round 5) — 8 waves, QB=128, grid 49x4 = 196 blocks.
// ---------------------------------------------------------------------------
__global__ __launch_bounds__(512) void flash3_kernel(
    const __bf16* __restrict__ qT, const __bf16* __restrict__ kpT,
    const __bf16* __restrict__ vp, __bf16* __restrict__ attT)
{
    __shared__ __attribute__((aligned(16))) __bf16 Kbuf[2][64 * 64]; // [k][c] swizzled
    __shared__ __attribute__((aligned(16))) __bf16 Ps[128 * 64];     // [q][k] swizzled
    __shared__ float scs[128];
    __shared__ float invl[128];

    int t = threadIdx.x;
    int lane = t & 63, w = t >> 6;
    int lm = lane & 15, lk = lane >> 4;
    int q0 = blockIdx.x * 128;
    int n  = blockIdx.y;
    int swz = (lm & 7) << 3;

    const __bf16* kbase = kpT + (size_t)n * LK * 64;
    const __bf16* vbase = vp  + (size_t)n * CVo * LK;

    bf16x8 qa[2];
    {
        const __bf16* qrow = &qT[((size_t)(n * LSP + q0 + w * 16 + lm)) * 64 + lk * 8];
        qa[0] = *reinterpret_cast<const bf16x8*>(qrow);
        qa[1] = *reinterpret_cast<const bf16x8*>(qrow + 32);
    }

    int kr = t >> 3, kc = t & 7;
    int kds = kr * 64 + ((kc * 8) ^ ((kr & 7) << 3));
    const __bf16* kgsrc = &kbase[(size_t)kr * 64 + kc * 8];

    const __bf16* vsrc[2][2];
    #pragma unroll
    for (int mi = 0; mi < 2; mi++)
        #pragma unroll
        for (int ks = 0; ks < 2; ks++)
            vsrc[mi][ks] = &vbase[(size_t)(w * 32 + mi * 16 + lm) * LK + ks * 32 + lk * 8];

    uint4 kreg;
    bf16x8 vcur[2][2], vnxt[2][2];

    kreg = *reinterpret_cast<const uint4*>(kgsrc);
    #pragma unroll
    for (int mi = 0; mi < 2; mi++)
        #pragma unroll
        for (int ks = 0; ks < 2; ks++)
            vcur[mi][ks] = *reinterpret_cast<const bf16x8*>(vsrc[mi][ks]);
    *reinterpret_cast<uint4*>(&Kbuf[0][kds]) = kreg;
    __syncthreads();

    f32x4 accO[2][8] = {};
    float m = -1e30f, l = 0.0f;
    int qrow = w * 16 + lm;

    for (int kt = 0; kt < 13; kt++) {
        int cur = kt & 1;
        bool have_next = (kt < 12);
        bool lastT = (kt == 12);
        if (have_next) {
            size_t off = (size_t)(kt + 1) * 64;
            kreg = *reinterpret_cast<const uint4*>(kgsrc + off * 64);
            #pragma unroll
            for (int mi = 0; mi < 2; mi++)
                #pragma unroll
                for (int ks = 0; ks < 2; ks++)
                    vnxt[mi][ks] = *reinterpret_cast<const bf16x8*>(vsrc[mi][ks] + off);
        }
        f32x4 accS[4] = {};
        #pragma unroll
        for (int kg = 0; kg < 4; kg++) {
            if (!lastT || kg == 0) {
                #pragma unroll
                for (int ks = 0; ks < 2; ks++) {
                    bf16x8 kf = *reinterpret_cast<const bf16x8*>(
                        &Kbuf[cur][(kg * 16 + lm) * 64 + ((ks * 32 + lk * 8) ^ swz)]);
                    accS[kg] = __builtin_amdgcn_mfma_f32_16x16x32_bf16(kf, qa[ks], accS[kg], 0, 0, 0);
                }
            } else {
                accS[kg][0] = -1e30f; accS[kg][1] = -1e30f;
                accS[kg][2] = -1e30f; accS[kg][3] = -1e30f;
            }
        }
        float v = -1e30f;
        #pragma unroll
        for (int kg = 0; kg < 4; kg++)
            #pragma unroll
            for (int r = 0; r < 4; r++) v = fmaxf(v, accS[kg][r]);
        v = fmaxf(v, __shfl_xor(v, 16));
        v = fmaxf(v, __shfl_xor(v, 32));
        float sc_out = 1.0f;
        if (__any(v - m > 8.0f)) {
            float mn = fmaxf(m, v);
            sc_out = __expf(m - mn);
            l *= sc_out;
            m = mn;
        }
        float lt = 0.0f;
        #pragma unroll
        for (int kg = 0; kg < 4; kg++) {
            bf16x4 pw;
            #pragma unroll
            for (int r = 0; r < 4; r++) {
                float p = __expf(accS[kg][r] - m);
                lt += p;
                pw[r] = (__bf16)p;
            }
            *reinterpret_cast<bf16x4*>(&Ps[qrow * 64 + ((kg * 16 + lk * 4) ^ swz)]) = pw;
        }
        lt += __shfl_xor(lt, 16);
        lt += __shfl_xor(lt, 32);
        l += lt;
        if (lk == 0) scs[qrow] = sc_out;
        __syncthreads();
        float s[8];
        #pragma unroll
        for (int ni = 0; ni < 8; ni++) s[ni] = scs[ni * 16 + lm];
        bool need = false;
        #pragma unroll
        for (int ni = 0; ni < 8; ni++) need = need || (s[ni] != 1.0f);
        if (__any(need)) {
            #pragma unroll
            for (int mi = 0; mi < 2; mi++)
                #pragma unroll
                for (int ni = 0; ni < 8; ni++)
                    #pragma unroll
                    for (int r = 0; r < 4; r++) accO[mi][ni][r] *= s[ni];
        }
        #pragma unroll
        for (int ks = 0; ks < 2; ks++) {
            bf16x8 pf[8];
            #pragma unroll
            for (int ni = 0; ni < 8; ni++)
                pf[ni] = *reinterpret_cast<const bf16x8*>(
                    &Ps[(ni * 16 + lm) * 64 + ((ks * 32 + lk * 8) ^ swz)]);
            #pragma unroll
            for (int mi = 0; mi < 2; mi++)
                #pragma unroll
                for (int ni = 0; ni < 8; ni++)
                    accO[mi][ni] = __builtin_amdgcn_mfma_f32_16x16x32_bf16(
                        vcur[mi][ks], pf[ni], accO[mi][ni], 0, 0, 0);
        }
        if (have_next)
            *reinterpret_cast<uint4*>(&Kbuf[cur ^ 1][kds]) = kreg;
        __syncthreads();
        #pragma unroll
        for (int mi = 0; mi < 2; mi++)
            #pragma unroll
            for (int ks = 0; ks < 2; ks++)
                vcur[mi][ks] = vnxt[mi][ks];
    }
    if (lk == 0) invl[qrow] = 1.0f / l;
    __syncthreads();
    #pragma unroll
    for (int ni = 0; ni < 8; ni++) {
        float inv = invl[ni * 16 + lm];
        __bf16* orow = &attT[((size_t)(n * LSP + q0 + ni * 16 + lm)) * CVo + w * 32 + lk * 4];
        #pragma unroll
        for (int mi = 0; mi < 2; mi++) {
            bf16x4 o;
            o[0] = (__bf16)(accO[mi][ni][0] * inv);
            o[1] = (__bf16)(accO[mi][ni][1] * inv);
            o[2] = (__bf16)(accO[mi][ni][2] * inv);
            o[3] = (__bf16)(accO[mi][ni][3] * inv);
            *reinterpret_cast<bf16x4*>(&orow[mi * 16]) = o;
        }
    }
}

// ---------------------------------------------------------------------------
// K6: Z MFMA GEMM + residual, register-double-buffered. A=attT(p), B=Wz(c).
// ---------------------------------------------------------------------------
__global__ __launch_bounds__(256) void z_gemm(const __bf16* __restrict__ Wzb,
                                              const __bf16* __restrict__ attT,
                                              const float* __restrict__ x,
                                              const float* __restrict__ yp,
                                              float* __restrict__ out)
{
    __shared__ __attribute__((aligned(16))) __bf16 As[2][128 * LDT];
    __shared__ __attribute__((aligned(16))) __bf16 Bs[2][128 * LDT];
    int t = threadIdx.x;
    int p0 = blockIdx.x * 128;
    int c0 = blockIdx.y * 128;
    int n  = blockIdx.z;
    int lane = t & 63, wid = t >> 6;
    int wm = wid >> 1, wn = wid & 1;
    int lm = lane & 15, lk = lane >> 4;

    const __bf16* asrc = &attT[((size_t)(n * LSP + p0 + (t >> 2))) * CVo + (t & 3) * 8];
    const __bf16* bsrc = &Wzb[(size_t)(c0 + (t >> 2)) * CVo + (t & 3) * 8];
    int dsoff = (t >> 2) * LDT + (t & 3) * 8;

    uint4 aa[2], bb[2];
    f32x4 acc[4][4] = {};

    aa[0] = *reinterpret_cast<const uint4*>(asrc);
    aa[1] = *reinterpret_cast<const uint4*>(asrc + 64 * CVo);
    bb[0] = *reinterpret_cast<const uint4*>(bsrc);
    bb[1] = *reinterpret_cast<const uint4*>(bsrc + 64 * CVo);
    *reinterpret_cast<uint4*>(&As[0][dsoff]) = aa[0];
    *reinterpret_cast<uint4*>(&As[0][dsoff + 64 * LDT]) = aa[1];
    *reinterpret_cast<uint4*>(&Bs[0][dsoff]) = bb[0];
    *reinterpret_cast<uint4*>(&Bs[0][dsoff + 64 * LDT]) = bb[1];
    __syncthreads();

    for (int kt = 0; kt < 8; kt++) {
        int cur = kt & 1;
        if (kt < 7) {
            int ko = (kt + 1) * 32;
            aa[0] = *reinterpret_cast<const uint4*>(asrc + ko);
            aa[1] = *reinterpret_cast<const uint4*>(asrc + 64 * CVo + ko);
            bb[0] = *reinterpret_cast<const uint4*>(bsrc + ko);
            bb[1] = *reinterpret_cast<const uint4*>(bsrc + 64 * CVo + ko);
        }
        bf16x8 a[4], b[4];
        #pragma unroll
        for (int mi = 0; mi < 4; mi++)
            a[mi] = *reinterpret_cast<const bf16x8*>(&As[cur][(wm * 64 + mi * 16 + lm) * LDT + lk * 8]);
        #pragma unroll
        for (int ni = 0; ni < 4; ni++)
            b[ni] = *reinterpret_cast<const bf16x8*>(&Bs[cur][(wn * 64 + ni * 16 + lm) * LDT + lk * 8]);
        #pragma unroll
        for (int mi = 0; mi < 4; mi++)
            #pragma unroll
            for (int ni = 0; ni < 4; ni++)
                acc[mi][ni] = __builtin_amdgcn_mfma_f32_16x16x32_bf16(a[mi], b[ni], acc[mi][ni], 0, 0, 0);
        if (kt < 7) {
            *reinterpret_cast<uint4*>(&As[cur ^ 1][dsoff]) = aa[0];
            *reinterpret_cast<uint4*>(&As[cur ^ 1][dsoff + 64 * LDT]) = aa[1];
            *reinterpret_cast<uint4*>(&Bs[cur ^ 1][dsoff]) = bb[0];
            *reinterpret_cast<uint4*>(&Bs[cur ^ 1][dsoff + 64 * LDT]) = bb[1];
        }
        __syncthreads();
    }

    float yv = yp[0];
    #pragma unroll
    for (int mi = 0; mi < 4; mi++) {
        int p = p0 + wm * 64 + mi * 16 + lk * 4;
        #pragma unroll
        for (int ni = 0; ni < 4; ni++) {
            int c = c0 + wn * 64 + ni * 16 + lm;
            size_t o = ((size_t)(n * CIN + c)) * LSP + p;
            const float4 xv = *reinterpret_cast<const float4*>(&x[o]);
            float4 ov;
            ov.x = yv * acc[mi][ni][0] + xv.x;
            ov.y = yv * acc[mi][ni][1] + xv.y;
            ov.z = yv * acc[mi][ni][2] + xv.z;
            ov.w = yv * acc[mi][ni][3] + xv.w;
            *reinterpret_cast<float4*>(&out[o]) = ov;
        }
    }
}

// ---------------------------------------------------------------------------
// Workspace layout (bf16 elems, 2 B each). Total 60.5 MB.
//   xT    [4][6272][512] @ 0            (12,845,056)
//   kT    [4][6272][64]  @ 12,845,056   ( 1,605,632)
//   vconv [4][256][6272] @ 14,450,688   ( 6,422,528)
//   qT    [4][6272][64]  @ 20,873,216   ( 1,605,632)
//   kpT   [4][784][64]   @ 22,478,848   (   200,704)
//   vp    [4][256][784]  @ 22,679,552   (   802,816)
//   attT  [4][6272][256] @ 23,482,368   ( 6,422,528)
//   Wqkv  [384][512]     @ 29,904,896   (   196,608)
//   Wzb   [512][256]     @ 30,101,504   (   131,072)
// ---------------------------------------------------------------------------
extern "C" void kernel_launch(void* const* d_in, const int* in_sizes, int n_in,
                              void* d_out, int out_size, void* d_ws, size_t ws_size,
                              hipStream_t stream)
{
    const float* x  = (const float*)d_in[0];
    const float* Wq = (const float*)d_in[1];
    const float* Wk = (const float*)d_in[2];
    const float* Wv = (const float*)d_in[3];
    const float* Wz = (const float*)d_in[4];
    const float* y  = (const float*)d_in[5];
    float* out = (float*)d_out;
    __bf16* ws = (__bf16*)d_ws;

    __bf16* xT    = ws;
    __bf16* kT    = ws + (size_t)12845056;
    __bf16* vconv = ws + (size_t)14450688;
    __bf16* qT    = ws + (size_t)20873216;
    __bf16* kpT   = ws + (size_t)22478848;
    __bf16* vp    = ws + (size_t)22679552;
    __bf16* attT  = ws + (size_t)23482368;
    __bf16* Wqkv  = ws + (size_t)29904896;
    __bf16* Wzb   = ws + (size_t)30101504;

    xt_kernel     <<<dim3(98, 8, 4), 256, 0, stream>>>(x, xT);
    wprep_kernel  <<<dim3(768), 256, 0, stream>>>(Wq, Wk, Wv, Wz, Wqkv, Wzb);
    qkv_gemm      <<<dim3(49, 3, 4), 256, 0, stream>>>(Wqkv, xT, qT, kT, vconv);
    poolk_kernel  <<<dim3(784), 256, 0, stream>>>(kT, kpT);
    poolv_kernel  <<<dim3(3136), 256, 0, stream>>>(vconv, vp);
    flash3_kernel <<<dim3(49, 4), 512, 0, stream>>>(qT, kpT, vp, attT);
    z_gemm        <<<dim3(49, 4, 4), 256, 0, stream>>>(Wzb, attT, x, y, out);
}